// Round 1
// baseline (8874.203 us; speedup 1.0000x reference)
//
#include <hip/hip_runtime.h>
#include <math.h>

#define LVLS 16
#define TSIZE (1u << 19)
#define TMASK (TSIZE - 1u)
#define NTHREADS 256

struct ResParams { float rf[LVLS]; };

__global__ __launch_bounds__(NTHREADS, 2)
void hashmlp_kernel(const float* __restrict__ x,
                    const float* __restrict__ t_ptr,
                    const float* __restrict__ tab_s,
                    const float* __restrict__ tab_d,
                    const float* __restrict__ w10,
                    const float* __restrict__ w11,
                    const float* __restrict__ w12,
                    const float* __restrict__ w20,
                    const float* __restrict__ w21,
                    const float* __restrict__ w22,
                    const float* __restrict__ alpha_ptr,
                    float* __restrict__ out,
                    int n, ResParams rp)
{
    __shared__ float smem[64 * NTHREADS];   // SoA: smem[i*256 + tid], 64 KB
    const int tid = threadIdx.x;
    const int gid = blockIdx.x * NTHREADS + tid;
    if (gid >= n) return;   // n divisible by 256; no barriers used in kernel

    const float px = x[3 * gid + 0];
    const float py = x[3 * gid + 1];
    const float pz = x[3 * gid + 2];
    const float tt = t_ptr[0];
    const float alpha = alpha_ptr[0];

    float feat[64];

    // ---------------- static encoder (3D, 8 corners) ----------------
    #pragma unroll
    for (int l = 0; l < LVLS; ++l) {
        const float r = rp.rf[l];
        const float fx = px * r, fy = py * r, fz = pz * r;
        const float gx = floorf(fx), gy = floorf(fy), gz = floorf(fz);
        const float wxp = fx - gx, wyp = fy - gy, wzp = fz - gz;
        const unsigned ux = (unsigned)(int)gx;
        const unsigned uy = (unsigned)(int)gy;
        const unsigned uz = (unsigned)(int)gz;
        const float* tb = tab_s + ((size_t)l << 20);   // l * T * 2
        float a0 = 0.f, a1 = 0.f;
        #pragma unroll
        for (int c = 0; c < 8; ++c) {
            const unsigned ox = (c >> 2) & 1, oy = (c >> 1) & 1, oz = c & 1;
            const unsigned h = ((ux + ox) * 1u)
                             ^ ((uy + oy) * 2654435761u)
                             ^ ((uz + oz) * 805459861u);
            const unsigned idx = h & TMASK;
            const float w = (ox ? wxp : 1.f - wxp)
                          * (oy ? wyp : 1.f - wyp)
                          * (oz ? wzp : 1.f - wzp);
            const float2 f = *reinterpret_cast<const float2*>(tb + ((size_t)idx * 2u));
            a0 = fmaf(w, f.x, a0);
            a1 = fmaf(w, f.y, a1);
        }
        feat[2 * l]     = a0;
        feat[2 * l + 1] = a1;
    }

    // ---------------- dynamic encoder (4D: x,y,z,t; t uniform) ----------------
    #pragma unroll
    for (int l = 0; l < LVLS; ++l) {
        const float r = rp.rf[l];
        const float fx = px * r, fy = py * r, fz = pz * r;
        const float gx = floorf(fx), gy = floorf(fy), gz = floorf(fz);
        const float wxp = fx - gx, wyp = fy - gy, wzp = fz - gz;
        const unsigned ux = (unsigned)(int)gx;
        const unsigned uy = (unsigned)(int)gy;
        const unsigned uz = (unsigned)(int)gz;
        const float ftp = tt * r;
        const float gt = floorf(ftp);
        const float wtp = ftp - gt;
        const unsigned ut = (unsigned)(int)gt;
        const unsigned ht0 = ut * 3674653429u;
        const unsigned ht1 = (ut + 1u) * 3674653429u;
        const float* tb = tab_d + ((size_t)l << 20);
        float a0 = 0.f, a1 = 0.f;
        #pragma unroll
        for (int c = 0; c < 8; ++c) {
            const unsigned ox = (c >> 2) & 1, oy = (c >> 1) & 1, oz = c & 1;
            const unsigned hs = ((ux + ox) * 1u)
                              ^ ((uy + oy) * 2654435761u)
                              ^ ((uz + oz) * 805459861u);
            const float ws = (ox ? wxp : 1.f - wxp)
                           * (oy ? wyp : 1.f - wyp)
                           * (oz ? wzp : 1.f - wzp);
            {   // t-plane 0 (offset bit o3=0, fastest-varying in reference order)
                const unsigned idx = (hs ^ ht0) & TMASK;
                const float w = ws * (1.f - wtp);
                const float2 f = *reinterpret_cast<const float2*>(tb + ((size_t)idx * 2u));
                a0 = fmaf(w, f.x, a0);
                a1 = fmaf(w, f.y, a1);
            }
            {   // t-plane 1
                const unsigned idx = (hs ^ ht1) & TMASK;
                const float w = ws * wtp;
                const float2 f = *reinterpret_cast<const float2*>(tb + ((size_t)idx * 2u));
                a0 = fmaf(w, f.x, a0);
                a1 = fmaf(w, f.y, a1);
            }
        }
        feat[32 + 2 * l] = a0;
        feat[33 + 2 * l] = a1;
    }

    // stash features in LDS (runtime-indexable layer input), keep copy in regs for blend
    #pragma unroll
    for (int i = 0; i < 64; ++i) smem[i * NTHREADS + tid] = feat[i];

    float acc[64];
    auto layer = [&](const float* __restrict__ W, bool do_relu) {
        #pragma unroll
        for (int j = 0; j < 64; ++j) acc[j] = 0.f;
        for (int i = 0; i < 64; ++i) {          // rolled; fi from LDS (own column)
            const float fi = smem[i * NTHREADS + tid];
            const float* wr = W + i * 64;       // uniform address -> s_load expected
            #pragma unroll
            for (int j = 0; j < 64; ++j)
                acc[j] = fmaf(fi, wr[j], acc[j]);
        }
        #pragma unroll
        for (int j = 0; j < 64; ++j) {
            const float v = do_relu ? fmaxf(acc[j], 0.f) : acc[j];
            smem[j * NTHREADS + tid] = v;       // in-place safe: all reads done
        }
    };

    layer(w10, true);
    layer(w11, true);
    layer(w12, true);

    // adaptive skip blend: out1*alpha + (1-alpha)*feat
    #pragma unroll
    for (int j = 0; j < 64; ++j) {
        const float o1 = smem[j * NTHREADS + tid];
        smem[j * NTHREADS + tid] = fmaf(o1, alpha, (1.f - alpha) * feat[j]);
    }

    layer(w20, true);
    layer(w21, true);

    // final head: [64] @ w22 [64,1]
    float o = 0.f;
    for (int i = 0; i < 64; ++i)
        o = fmaf(smem[i * NTHREADS + tid], w22[i], o);
    out[gid] = o;
}

extern "C" void kernel_launch(void* const* d_in, const int* in_sizes, int n_in,
                              void* d_out, int out_size, void* d_ws, size_t ws_size,
                              hipStream_t stream) {
    (void)n_in; (void)d_ws; (void)ws_size; (void)out_size;
    const float* x     = (const float*)d_in[0];
    const float* t     = (const float*)d_in[1];
    const float* tabs  = (const float*)d_in[2];
    const float* tabd  = (const float*)d_in[3];
    const float* w10   = (const float*)d_in[4];
    const float* w11   = (const float*)d_in[5];
    const float* w12   = (const float*)d_in[6];
    const float* w20   = (const float*)d_in[7];
    const float* w21   = (const float*)d_in[8];
    const float* w22   = (const float*)d_in[9];
    const float* alpha = (const float*)d_in[10];
    float* out = (float*)d_out;
    const int n = in_sizes[0] / 3;

    // Replicate Python's float64 RES computation exactly (same glibc pow).
    ResParams rp;
    const double b = pow(2048.0 / 16.0, 1.0 / 15.0);
    for (int l = 0; l < LVLS; ++l) {
        rp.rf[l] = (float)(int)floor(16.0 * pow(b, (double)l));
    }

    dim3 grid((n + NTHREADS - 1) / NTHREADS), block(NTHREADS);
    hipLaunchKernelGGL(hashmlp_kernel, grid, block, 0, stream,
                       x, t, tabs, tabd, w10, w11, w12, w20, w21, w22,
                       alpha, out, n, rp);
}

// Round 2
// 2950.845 us; speedup vs baseline: 3.0073x; 3.0073x over previous
//
#include <hip/hip_runtime.h>
#include <math.h>

#define LVLS 16
#define TMASK ((1u << 19) - 1u)
#define NT 256
#define TSLICE (1u << 20)   // floats per level slice (T*F)
#define KPL (1u << 19)      // table entries per level

struct ResParams { float rf[LVLS]; };

__device__ __forceinline__ unsigned hash3(unsigned ux, unsigned uy, unsigned uz) {
    return ux ^ (uy * 2654435761u) ^ (uz * 805459861u);
}

// ---------------- build fused table E[l][k] = {tab_s[l][k], time-blended tab_d[l][k]} ----
__global__ __launch_bounds__(NT, 8)
void build_E(const float* __restrict__ tabs, const float* __restrict__ tabd,
             const float* __restrict__ t_ptr, float4* __restrict__ E, ResParams rp)
{
    const unsigned idx = blockIdx.x * NT + threadIdx.x;   // 16 * 512K threads
    const unsigned l = idx >> 19;
    const unsigned k = idx & TMASK;
    const float r = rp.rf[l];
    const float tt = t_ptr[0];
    const float ft = tt * r;
    const float gt = floorf(ft);
    const float wt = ft - gt;
    const unsigned ut = (unsigned)(int)gt;
    const unsigned c0 = (ut * 3674653429u) & TMASK;
    const unsigned c1 = ((ut + 1u) * 3674653429u) & TMASK;
    const float* ts = tabs + (size_t)l * TSLICE;
    const float* td = tabd + (size_t)l * TSLICE;
    const float2 s  = *(const float2*)(ts + (size_t)k * 2u);
    const float2 d0 = *(const float2*)(td + (size_t)(k ^ c0) * 2u);
    const float2 d1 = *(const float2*)(td + (size_t)(k ^ c1) * 2u);
    const float om = 1.f - wt;
    E[idx] = make_float4(s.x, s.y,
                         om * d0.x + wt * d1.x,
                         om * d0.y + wt * d1.y);
}

// ---------------- per-level encoder pass: 8 float4 gathers from an 8MB slice ----------
__global__ __launch_bounds__(NT, 8)
void enc_level(const float* __restrict__ x, const float4* __restrict__ E,
               float2* __restrict__ fbs, float2* __restrict__ fbd,
               int npts, float r)
{
    const int gid = blockIdx.x * NT + threadIdx.x;
    if (gid >= npts) return;
    const float px = x[3 * gid + 0];
    const float py = x[3 * gid + 1];
    const float pz = x[3 * gid + 2];
    const float fx = px * r, fy = py * r, fz = pz * r;
    const float gx = floorf(fx), gy = floorf(fy), gz = floorf(fz);
    const float wx = fx - gx, wy = fy - gy, wz = fz - gz;
    const unsigned ux = (unsigned)(int)gx;
    const unsigned uy = (unsigned)(int)gy;
    const unsigned uz = (unsigned)(int)gz;
    float a0 = 0.f, a1 = 0.f, b0 = 0.f, b1 = 0.f;
    #pragma unroll
    for (int c = 0; c < 8; ++c) {
        const unsigned ox = (c >> 2) & 1, oy = (c >> 1) & 1, oz = c & 1;
        const unsigned kk = hash3(ux + ox, uy + oy, uz + oz) & TMASK;
        const float w = (ox ? wx : 1.f - wx)
                      * (oy ? wy : 1.f - wy)
                      * (oz ? wz : 1.f - wz);
        const float4 e = E[kk];
        a0 = fmaf(w, e.x, a0);
        a1 = fmaf(w, e.y, a1);
        b0 = fmaf(w, e.z, b0);
        b1 = fmaf(w, e.w, b1);
    }
    fbs[gid] = make_float2(a0, a1);
    fbd[gid] = make_float2(b0, b1);
}

// ---------------- MLP over staged features --------------------------------------------
__global__ __launch_bounds__(NT, 2)
void mlp_kernel(const float2* __restrict__ fb, long cp,
                const float* __restrict__ w10, const float* __restrict__ w11,
                const float* __restrict__ w12, const float* __restrict__ w20,
                const float* __restrict__ w21, const float* __restrict__ w22,
                const float* __restrict__ alpha_ptr,
                float* __restrict__ out, int npts)
{
    __shared__ float smem[64 * NT];
    const int tid = threadIdx.x;
    const int gid = blockIdx.x * NT + tid;
    if (gid >= npts) return;

    float feat[64];
    #pragma unroll
    for (int p = 0; p < 32; ++p) {
        const float2 v = fb[(long)p * cp + gid];
        feat[2 * p]     = v.x;
        feat[2 * p + 1] = v.y;
        smem[(2 * p) * NT + tid]     = v.x;
        smem[(2 * p + 1) * NT + tid] = v.y;
    }

    float acc[64];
    auto layer = [&](const float* __restrict__ W, bool do_relu) {
        #pragma unroll
        for (int j = 0; j < 64; ++j) acc[j] = 0.f;
        for (int i = 0; i < 64; ++i) {
            const float fi = smem[i * NT + tid];
            const float* wr = W + i * 64;
            #pragma unroll
            for (int j = 0; j < 64; ++j)
                acc[j] = fmaf(fi, wr[j], acc[j]);
        }
        #pragma unroll
        for (int j = 0; j < 64; ++j) {
            const float v = do_relu ? fmaxf(acc[j], 0.f) : acc[j];
            smem[j * NT + tid] = v;
        }
    };

    layer(w10, true);
    layer(w11, true);
    layer(w12, true);

    const float alpha = alpha_ptr[0];
    #pragma unroll
    for (int j = 0; j < 64; ++j) {
        const float o1 = smem[j * NT + tid];
        smem[j * NT + tid] = fmaf(o1, alpha, (1.f - alpha) * feat[j]);
    }

    layer(w20, true);
    layer(w21, true);

    float o = 0.f;
    for (int i = 0; i < 64; ++i)
        o = fmaf(smem[i * NT + tid], w22[i], o);
    out[gid] = o;
}

// ---------------- fallback: fused single kernel (round-1, passed) ---------------------
__global__ __launch_bounds__(NT, 2)
void hashmlp_fused(const float* __restrict__ x, const float* __restrict__ t_ptr,
                   const float* __restrict__ tab_s, const float* __restrict__ tab_d,
                   const float* __restrict__ w10, const float* __restrict__ w11,
                   const float* __restrict__ w12, const float* __restrict__ w20,
                   const float* __restrict__ w21, const float* __restrict__ w22,
                   const float* __restrict__ alpha_ptr, float* __restrict__ out,
                   int n, ResParams rp)
{
    __shared__ float smem[64 * NT];
    const int tid = threadIdx.x;
    const int gid = blockIdx.x * NT + tid;
    if (gid >= n) return;
    const float px = x[3 * gid], py = x[3 * gid + 1], pz = x[3 * gid + 2];
    const float tt = t_ptr[0];
    const float alpha = alpha_ptr[0];
    float feat[64];
    #pragma unroll
    for (int l = 0; l < LVLS; ++l) {
        const float r = rp.rf[l];
        const float fx = px * r, fy = py * r, fz = pz * r;
        const float gx = floorf(fx), gy = floorf(fy), gz = floorf(fz);
        const float wx = fx - gx, wy = fy - gy, wz = fz - gz;
        const unsigned ux = (unsigned)(int)gx, uy = (unsigned)(int)gy, uz = (unsigned)(int)gz;
        const float* tb = tab_s + ((size_t)l << 20);
        float a0 = 0.f, a1 = 0.f;
        #pragma unroll
        for (int c = 0; c < 8; ++c) {
            const unsigned ox = (c >> 2) & 1, oy = (c >> 1) & 1, oz = c & 1;
            const unsigned idx = hash3(ux + ox, uy + oy, uz + oz) & TMASK;
            const float w = (ox ? wx : 1.f - wx) * (oy ? wy : 1.f - wy) * (oz ? wz : 1.f - wz);
            const float2 f = *reinterpret_cast<const float2*>(tb + ((size_t)idx * 2u));
            a0 = fmaf(w, f.x, a0); a1 = fmaf(w, f.y, a1);
        }
        feat[2 * l] = a0; feat[2 * l + 1] = a1;
    }
    #pragma unroll
    for (int l = 0; l < LVLS; ++l) {
        const float r = rp.rf[l];
        const float fx = px * r, fy = py * r, fz = pz * r;
        const float gx = floorf(fx), gy = floorf(fy), gz = floorf(fz);
        const float wx = fx - gx, wy = fy - gy, wz = fz - gz;
        const unsigned ux = (unsigned)(int)gx, uy = (unsigned)(int)gy, uz = (unsigned)(int)gz;
        const float ftp = tt * r;
        const float gt = floorf(ftp);
        const float wtp = ftp - gt;
        const unsigned ut = (unsigned)(int)gt;
        const unsigned ht0 = ut * 3674653429u;
        const unsigned ht1 = (ut + 1u) * 3674653429u;
        const float* tb = tab_d + ((size_t)l << 20);
        float a0 = 0.f, a1 = 0.f;
        #pragma unroll
        for (int c = 0; c < 8; ++c) {
            const unsigned ox = (c >> 2) & 1, oy = (c >> 1) & 1, oz = c & 1;
            const unsigned hs = hash3(ux + ox, uy + oy, uz + oz);
            const float ws = (ox ? wx : 1.f - wx) * (oy ? wy : 1.f - wy) * (oz ? wz : 1.f - wz);
            {
                const unsigned idx = (hs ^ ht0) & TMASK;
                const float w = ws * (1.f - wtp);
                const float2 f = *reinterpret_cast<const float2*>(tb + ((size_t)idx * 2u));
                a0 = fmaf(w, f.x, a0); a1 = fmaf(w, f.y, a1);
            }
            {
                const unsigned idx = (hs ^ ht1) & TMASK;
                const float w = ws * wtp;
                const float2 f = *reinterpret_cast<const float2*>(tb + ((size_t)idx * 2u));
                a0 = fmaf(w, f.x, a0); a1 = fmaf(w, f.y, a1);
            }
        }
        feat[32 + 2 * l] = a0; feat[33 + 2 * l] = a1;
    }
    #pragma unroll
    for (int i = 0; i < 64; ++i) smem[i * NT + tid] = feat[i];
    float acc[64];
    auto layer = [&](const float* __restrict__ W, bool do_relu) {
        #pragma unroll
        for (int j = 0; j < 64; ++j) acc[j] = 0.f;
        for (int i = 0; i < 64; ++i) {
            const float fi = smem[i * NT + tid];
            const float* wr = W + i * 64;
            #pragma unroll
            for (int j = 0; j < 64; ++j) acc[j] = fmaf(fi, wr[j], acc[j]);
        }
        #pragma unroll
        for (int j = 0; j < 64; ++j) {
            const float v = do_relu ? fmaxf(acc[j], 0.f) : acc[j];
            smem[j * NT + tid] = v;
        }
    };
    layer(w10, true); layer(w11, true); layer(w12, true);
    #pragma unroll
    for (int j = 0; j < 64; ++j) {
        const float o1 = smem[j * NT + tid];
        smem[j * NT + tid] = fmaf(o1, alpha, (1.f - alpha) * feat[j]);
    }
    layer(w20, true); layer(w21, true);
    float o = 0.f;
    for (int i = 0; i < 64; ++i) o = fmaf(smem[i * NT + tid], w22[i], o);
    out[gid] = o;
}

extern "C" void kernel_launch(void* const* d_in, const int* in_sizes, int n_in,
                              void* d_out, int out_size, void* d_ws, size_t ws_size,
                              hipStream_t stream) {
    (void)n_in; (void)out_size;
    const float* x     = (const float*)d_in[0];
    const float* t     = (const float*)d_in[1];
    const float* tabs  = (const float*)d_in[2];
    const float* tabd  = (const float*)d_in[3];
    const float* w10   = (const float*)d_in[4];
    const float* w11   = (const float*)d_in[5];
    const float* w12   = (const float*)d_in[6];
    const float* w20   = (const float*)d_in[7];
    const float* w21   = (const float*)d_in[8];
    const float* w22   = (const float*)d_in[9];
    const float* alpha = (const float*)d_in[10];
    float* out = (float*)d_out;
    const int n = in_sizes[0] / 3;

    ResParams rp;
    const double b = pow(2048.0 / 16.0, 1.0 / 15.0);
    for (int l = 0; l < LVLS; ++l)
        rp.rf[l] = (float)(int)floor(16.0 * pow(b, (double)l));

    const size_t E_BYTES = (size_t)LVLS * KPL * 16u;   // 128 MB
    if (ws_size < E_BYTES + 256u * 256u) {
        // workspace too small: fused fallback
        dim3 grid((n + NT - 1) / NT), block(NT);
        hipLaunchKernelGGL(hashmlp_fused, grid, block, 0, stream,
                           x, t, tabs, tabd, w10, w11, w12, w20, w21, w22,
                           alpha, out, n, rp);
        return;
    }

    float4* E = (float4*)d_ws;
    float2* fb = (float2*)((char*)d_ws + E_BYTES);
    long cp_cap = (long)((ws_size - E_BYTES) / 256u) & ~255L;  // points per chunk
    long cp = cp_cap < (long)n ? cp_cap : (long)n;

    {   // build fused table (once per launch)
        const unsigned total = LVLS * KPL;
        hipLaunchKernelGGL(build_E, dim3(total / NT), dim3(NT), 0, stream,
                           tabs, tabd, t, E, rp);
    }

    for (long start = 0; start < n; start += cp) {
        const long m = (n - start) < cp ? (n - start) : cp;
        dim3 grid((unsigned)((m + NT - 1) / NT)), block(NT);
        for (int l = 0; l < LVLS; ++l) {
            hipLaunchKernelGGL(enc_level, grid, block, 0, stream,
                               x + 3 * start,
                               E + (size_t)l * KPL,
                               fb + (size_t)l * cp,
                               fb + (size_t)(LVLS + l) * cp,
                               (int)m, rp.rf[l]);
        }
        hipLaunchKernelGGL(mlp_kernel, grid, block, 0, stream,
                           fb, cp, w10, w11, w12, w20, w21, w22,
                           alpha, out + start, (int)m);
    }
}